// Round 1
// 321.943 us; speedup vs baseline: 1.3294x; 1.3294x over previous
//
#include <hip/hip_runtime.h>

// MorphogenField: 10 fused diffusion+decay steps, B=8,M=4,H=1024,W=1024 fp32.
// v2: register-resident tile. One block = one 64x64 output tile; each lane owns
// a 3-row x 12-col sub-tile in VGPRs across all 10 steps. LDS holds only the
// strip boundary rows (top+bottom of each 3-row strip) for vertical exchange.
// vs v1 (full-tile LDS ping-pong, 63KB/block, 2 blocks/CU, VALUBusy 46%):
//   LDS/block 63KB -> 25.6KB  => 4 blocks/CU (16 waves/CU, __launch_bounds__(256,4))
//   LDS ops/lane/step 24 -> 12 b128, no per-step tile addressing.
constexpr int Hv = 1024, Wv = 1024;
constexpr int TILE   = 64;
constexpr int HALO_R = 10;               // rows halo = steps (exact margin)
constexpr int CHALO  = 16;               // cols halo (float4-aligned, margin 6)
constexpr int COLS   = TILE + 2*CHALO;   // 96 = 8 lanes x 12 cols
constexpr int NSTRIP = 32;               // 3 rows/strip -> rows 0..95 (84 useful)
constexpr int XPITCH = 100;              // pad: 100%32=4 spreads bank quads; 16B-aligned
constexpr int STEPS  = 10;               // from setup_inputs()

// o = c*(1-4d-k) + d*(l+r+u+dn): 3 adds + 1 mul + 1 fma per element.
__device__ __forceinline__ float4 upd4(const float4 c, const float4 u, const float4 d,
                                       const float lf, const float rt,
                                       const float dif, const float cdec)
{
    float4 o;
    o.x = fmaf(cdec, c.x, dif * ((lf  + c.y) + (u.x + d.x)));
    o.y = fmaf(cdec, c.y, dif * ((c.x + c.z) + (u.y + d.y)));
    o.z = fmaf(cdec, c.z, dif * ((c.y + c.w) + (u.z + d.z)));
    o.w = fmaf(cdec, c.w, dif * ((c.z + rt ) + (u.w + d.w)));
    return o;
}

// staging load with the same edge-broadcast semantics as v1
__device__ __forceinline__ float4 ldrow4(const float* __restrict__ rowp, int gc)
{
    if (gc < 0)        { float e = rowp[0];      return make_float4(e, e, e, e); }
    if (gc > Wv - 4)   { float e = rowp[Wv - 1]; return make_float4(e, e, e, e); }
    return *(const float4*)(rowp + gc);
}

// one row update: center row P, up-row U, down-row D (12 cols each).
// Shuffles crossing a wave/strip boundary feed only junk cols 0/95 (finite).
__device__ __forceinline__ void rowupd(const float4& P0, const float4& P1, const float4& P2,
                                       const float4& U0, const float4& U1, const float4& U2,
                                       const float4& D0, const float4& D1, const float4& D2,
                                       bool lclamp, bool rclamp, float dif, float cdec,
                                       float4& O0, float4& O1, float4& O2)
{
    float lv = __shfl_up(P2.w, 1);        // left of col 12h
    float rv = __shfl_down(P0.x, 1);      // right of col 12h+11
    float lA = lclamp ? P1.x : P0.w;      // left of P1.x (global col 0)
    float rA = rclamp ? P1.w : P2.x;      // right of P1.w (global col 1023)
    O0 = upd4(P0, U0, D0, lv,   P1.x, dif, cdec);
    O1 = upd4(P1, U1, D1, lA,   rA,   dif, cdec);
    O2 = upd4(P2, U2, D2, P1.w, rv,   dif, cdec);
}

__global__ __launch_bounds__(256, 4)
void morpho_reg(const float* __restrict__ src, float* __restrict__ dst,
                const float* __restrict__ dr,  const float* __restrict__ kr)
{
    __shared__ float xtop[NSTRIP * XPITCH];   // row 3s of each strip
    __shared__ float xbot[NSTRIP * XPITCH];   // row 3s+2 of each strip
    // total 2*32*100*4 = 25,600 B

    const int b  = blockIdx.x;
    const int bx = b & 15, by = (b >> 4) & 15, plane = b >> 8;
    const float dif  = dr[plane & 3];
    const float dec  = kr[plane & 3];
    const float cdec = 1.0f - 4.0f * dif - dec;
    const int r0 = by * TILE, c0 = bx * TILE;
    const int tid = threadIdx.x;
    const int h = tid & 7;                // col group: cols 12h..12h+11
    const int s = tid >> 3;               // strip: rows 3s..3s+2

    const float* sp = src + ((size_t)plane << 20);

    // ---- stage own 3x12 sub-tile into registers (globally clamped) ----
    float4 A0, A1, A2, B0, B1, B2, C0, C1, C2;   // rows 3s, 3s+1, 3s+2
    {
        const int rb = r0 - HALO_R + 3 * s;
        const int cb = c0 - CHALO + 12 * h;
        const float* rp0 = sp + ((size_t)min(max(rb    , 0), Hv - 1) << 10);
        const float* rp1 = sp + ((size_t)min(max(rb + 1, 0), Hv - 1) << 10);
        const float* rp2 = sp + ((size_t)min(max(rb + 2, 0), Hv - 1) << 10);
        A0 = ldrow4(rp0, cb); A1 = ldrow4(rp0, cb + 4); A2 = ldrow4(rp0, cb + 8);
        B0 = ldrow4(rp1, cb); B1 = ldrow4(rp1, cb + 4); B2 = ldrow4(rp1, cb + 8);
        C0 = ldrow4(rp2, cb); C1 = ldrow4(rp2, cb + 4); C2 = ldrow4(rp2, cb + 8);
    }

    // LDS exchange addresses (fixed for the whole kernel)
    float*       wt = &xtop[s * XPITCH + 12 * h];
    float*       wb = &xbot[s * XPITCH + 12 * h];
    const float* ru = &xbot[max(s - 1, 0)          * XPITCH + 12 * h]; // row 3s-1
    const float* rd = &xtop[min(s + 1, NSTRIP - 1) * XPITCH + 12 * h]; // row 3s+3

    const bool lclamp = (bx == 0)  && (h == 1);
    const bool rclamp = (bx == 15) && (h == 6);
    const bool tclamp = (by == 0)  && (s == 3);   // local row 10 == global row 0
    const bool bclamp = (by == 15) && (s == 24);  // local row 73 == global row 1023

    #pragma unroll
    for (int t = 0; t < STEPS; ++t) {
        // publish boundary rows (current values)
        *(float4*)(wt + 0) = A0; *(float4*)(wt + 4) = A1; *(float4*)(wt + 8) = A2;
        *(float4*)(wb + 0) = C0; *(float4*)(wb + 4) = C1; *(float4*)(wb + 8) = C2;
        __syncthreads();
        float4 U0 = *(const float4*)(ru + 0), U1 = *(const float4*)(ru + 4), U2 = *(const float4*)(ru + 8);
        float4 D0 = *(const float4*)(rd + 0), D1 = *(const float4*)(rd + 4), D2 = *(const float4*)(rd + 8);
        __syncthreads();   // reads done; next iteration may overwrite

        // domain-edge row clamps hit only middle rows (up/down stay in-register)
        float4 MU0 = tclamp ? B0 : A0, MU1 = tclamp ? B1 : A1, MU2 = tclamp ? B2 : A2;
        float4 MD0 = bclamp ? B0 : C0, MD1 = bclamp ? B1 : C1, MD2 = bclamp ? B2 : C2;

        float4 N10, N11, N12;  // middle row first: register-only, covers LDS latency
        rowupd(B0, B1, B2, MU0, MU1, MU2, MD0, MD1, MD2, lclamp, rclamp, dif, cdec, N10, N11, N12);
        float4 N00, N01, N02;
        rowupd(A0, A1, A2, U0, U1, U2, B0, B1, B2, lclamp, rclamp, dif, cdec, N00, N01, N02);
        float4 N20, N21, N22;
        rowupd(C0, C1, C2, B0, B1, B2, D0, D1, D2, lclamp, rclamp, dif, cdec, N20, N21, N22);

        A0 = N00; A1 = N01; A2 = N02;   // full unroll: copies SSA-renamed away
        B0 = N10; B1 = N11; B2 = N12;
        C0 = N20; C1 = N21; C2 = N22;
    }

    // ---- store center 64x64 (local rows 10..73, cols 16..79) from registers ----
    float* dp = dst + ((size_t)plane << 20);
    const int cbase = 12 * h - CHALO;     // tile-relative col of this lane's first f4

#define STORE_ROW(LR, P0, P1, P2) do {                                              \
        const int lr_ = (LR);                                                       \
        if (lr_ >= HALO_R && lr_ < HALO_R + TILE) {                                 \
            float* rp_ = dp + ((size_t)(r0 + lr_ - HALO_R) << 10) + c0;             \
            if (cbase     >= 0 && cbase     <= TILE - 4) *(float4*)(rp_ + cbase)     = P0; \
            if (cbase + 4 >= 0 && cbase + 4 <= TILE - 4) *(float4*)(rp_ + cbase + 4) = P1; \
            if (cbase + 8 >= 0 && cbase + 8 <= TILE - 4) *(float4*)(rp_ + cbase + 8) = P2; \
        } } while (0)

    STORE_ROW(3 * s + 0, A0, A1, A2);
    STORE_ROW(3 * s + 1, B0, B1, B2);
    STORE_ROW(3 * s + 2, C0, C1, C2);
#undef STORE_ROW
}

extern "C" void kernel_launch(void* const* d_in, const int* in_sizes, int n_in,
                              void* d_out, int out_size, void* d_ws, size_t ws_size,
                              hipStream_t stream) {
    const float* init = (const float*)d_in[0];
    const float* dr   = (const float*)d_in[1];
    const float* kr   = (const float*)d_in[2];
    float* out = (float*)d_out;
    // 16x16 tiles per plane x 32 planes
    morpho_reg<<<dim3(16 * 16 * 32), dim3(256), 0, stream>>>(init, out, dr, kr);
}